// Round 17
// baseline (185.119 us; speedup 1.0000x reference)
//
#include <hip/hip_runtime.h>

// Fused GRU (Keras reset_after=True, relu) for MI355X — round 17.
// r16 base (170.6 µs). Single change: z and r gate chains use packed f16
// FMA (v_pk_fma_f16, 2 MACs/instr at f16 full rate) instead of dot2;
// candidate (rh) chain stays f32-accumulate dot2 for precision. z/r f16
// accumulation error is damped by the 0.25 sigmoid slope + convex h update.
// Block = 256 thr (4 waves) = 2 batch rows. Grid = 256 = 1 block/CU, 1 pass.
//   Wave 0/1: recurrence rows 0/1 (X chunk-preload, U f16-packed resident,
//             readlane->SGPR broadcast, fast sigmoid, z-chains first).
//   Wave 2/3: x-proj producers (bf16x3 MFMA, W frags resident, dbuf Xb).

#define B_SZ   512
#define T_SZ   512
#define F_SZ   128
#define UN     64
#define G3     192
#define CHUNK  16
#define NCHUNK (T_SZ / CHUNK)
#define NCLS   10
#define GP     196

using short8 = __attribute__((ext_vector_type(8))) short;
using f32x4  = __attribute__((ext_vector_type(4))) float;
using h2     = __attribute__((ext_vector_type(2))) __fp16;
using h2v    = __attribute__((ext_vector_type(2))) _Float16;
typedef unsigned int u32;

union S8 { short8 s; u32 u[4]; };
union HU { h2 h; u32 u; };
union HV { h2v h; u32 u; };

__device__ __forceinline__ u32 permb(u32 a, u32 b, u32 sel) {
    return __builtin_amdgcn_perm(a, b, sel);
}
__device__ __forceinline__ unsigned short f2bf_rn(float f) {
    u32 u = __float_as_uint(f);
    u32 r = u + 0x7FFFu + ((u >> 16) & 1u);
    return (unsigned short)(r >> 16);
}
__device__ __forceinline__ float bf2f(unsigned short s) {
    return __uint_as_float(((u32)s) << 16);
}
__device__ __forceinline__ float sigmoid_fast(float x) {
    float t = -1.44269504f * x;
    float e; asm("v_exp_f32 %0, %1" : "=v"(e) : "v"(t));
    float d = 1.0f + e;
    float r; asm("v_rcp_f32 %0, %1" : "=v"(r) : "v"(d));
    return r;
}
__device__ __forceinline__ void split_pair(float f0, float f1, u32 &hi, u32 &lo) {
    u32 u0 = __float_as_uint(f0) & 0xffff0000u;
    u32 u1 = __float_as_uint(f1) & 0xffff0000u;
    float l0 = f0 - __uint_as_float(u0);
    float l1 = f1 - __uint_as_float(u1);
    hi = permb(u1, u0, 0x07060302u);
    lo = permb(__float_as_uint(l1), __float_as_uint(l0), 0x07060302u);
}
__device__ __forceinline__ u32 packf16(float f0, float f1) {
    __fp16 a = (__fp16)f0, b = (__fp16)f1;
    return (u32)__builtin_bit_cast(unsigned short, a)
         | ((u32)__builtin_bit_cast(unsigned short, b) << 16);
}
__device__ __forceinline__ float dot2acc(u32 hp, u32 up, float acc) {
#if __has_builtin(__builtin_amdgcn_fdot2)
    HU a, b; a.u = hp; b.u = up;
    return __builtin_amdgcn_fdot2(a.h, b.h, acc, false);
#else
    HU a, b; a.u = hp; b.u = up;
    acc = fmaf((float)a.h[0], (float)b.h[0], acc);
    return fmaf((float)a.h[1], (float)b.h[1], acc);
#endif
}
// packed f16 fma: acc = a*b + acc  (v_pk_fma_f16)
__device__ __forceinline__ h2v pkfma(u32 a, u32 b, h2v acc) {
    HV x, y; x.u = a; y.u = b;
#if __has_builtin(__builtin_elementwise_fma)
    return __builtin_elementwise_fma(x.h, y.h, acc);
#else
    h2v r;
    r[0] = (_Float16)fmaf((float)x.h[0], (float)y.h[0], (float)acc[0]);
    r[1] = (_Float16)fmaf((float)x.h[1], (float)y.h[1], (float)acc[1]);
    return r;
#endif
}
__device__ __forceinline__ u32 pkrtz(float f0, float f1) {
#if __has_builtin(__builtin_amdgcn_cvt_pkrtz)
    h2 v = __builtin_amdgcn_cvt_pkrtz(f0, f1);
    return __builtin_bit_cast(u32, v);
#else
    return packf16(f0, f1);
#endif
}
#define WAVE_SYNC() asm volatile("s_waitcnt lgkmcnt(0)" ::: "memory")
#define MFMA16(A, B, C) __builtin_amdgcn_mfma_f32_16x16x32_bf16((A), (B), (C), 0, 0, 0)

__global__ __launch_bounds__(256, 1)
void gru_fused17(const float* __restrict__ inp,   // [512,512,128]
                 const float* __restrict__ W,     // [128,192]
                 const float* __restrict__ U,     // [64,192]
                 const float* __restrict__ bias,  // [2,192]
                 const float* __restrict__ W1,    // [64,64]
                 const float* __restrict__ b1,    // [64]
                 const float* __restrict__ W2,    // [64,10]
                 const float* __restrict__ b2,    // [10]
                 float* __restrict__ out)         // [512,10]
{
    const int tid  = threadIdx.x;
    const int wv   = tid >> 6;
    const int lane = tid & 63;
    const int l15  = lane & 15;
    const int l4   = lane >> 4;
    const int r0   = blockIdx.x * 2;

    __shared__ __align__(16) float Xb[2][2][CHUNK][GP];
    __shared__ float hb[2][UN];
    __shared__ float sc[2][UN];
    __shared__ float lg[2][NCLS];

    if (wv >= 2) {
        // ======================= producers (r7-identical) =======================
        const int tb = 6 * (wv - 2);
        short8 Wh[6][4], Wl[6][4];
        float  b0c[6];
        #pragma unroll
        for (int nt = 0; nt < 6; ++nt) {
            const int col = 16 * (tb + nt) + l15;
            b0c[nt] = bias[col];
            #pragma unroll
            for (int kt = 0; kt < 4; ++kt) {
                #pragma unroll
                for (int e = 0; e < 8; ++e) {
                    float w = W[(size_t)(32 * kt + 8 * l4 + e) * G3 + col];
                    unsigned short hi = f2bf_rn(w);
                    Wh[nt][kt][e] = (short)hi;
                    Wl[nt][kt][e] = (short)f2bf_rn(w - bf2f(hi));
                }
            }
        }

        auto produce = [&](int cn) {
            const int bn = cn & 1;
            #pragma unroll
            for (int r = 0; r < 2; ++r) {
                const float* ap = inp + (size_t)(r0 + r) * T_SZ * F_SZ
                                + (size_t)(cn * CHUNK + l15) * F_SZ + 8 * l4;
                f32x4 acc[6];
                #pragma unroll
                for (int nt = 0; nt < 6; ++nt) acc[nt] = (f32x4){0.f, 0.f, 0.f, 0.f};
                #pragma unroll
                for (int kt = 0; kt < 4; ++kt) {
                    f32x4 v0 = *(const f32x4*)(ap + 32 * kt);
                    f32x4 v1 = *(const f32x4*)(ap + 32 * kt + 4);
                    S8 Ah, Al;
                    split_pair(v0[0], v0[1], Ah.u[0], Al.u[0]);
                    split_pair(v0[2], v0[3], Ah.u[1], Al.u[1]);
                    split_pair(v1[0], v1[1], Ah.u[2], Al.u[2]);
                    split_pair(v1[2], v1[3], Ah.u[3], Al.u[3]);
                    #pragma unroll
                    for (int nt = 0; nt < 6; ++nt) {
                        acc[nt] = MFMA16(Ah.s, Wh[nt][kt], acc[nt]);
                        acc[nt] = MFMA16(Al.s, Wh[nt][kt], acc[nt]);
                        acc[nt] = MFMA16(Ah.s, Wl[nt][kt], acc[nt]);
                    }
                }
                #pragma unroll
                for (int nt = 0; nt < 6; ++nt) {
                    const int col = 16 * (tb + nt) + l15;
                    #pragma unroll
                    for (int q = 0; q < 4; ++q)
                        Xb[bn][r][4 * l4 + q][col] = acc[nt][q] + b0c[nt];
                }
            }
        };

        produce(0);
        __syncthreads();
        for (int c = 0; c < NCHUNK; ++c) {
            if (c + 1 < NCHUNK) produce(c + 1);
            __syncthreads();
        }
    } else {
        // ======================= recurrence (row = wv) =======================
        u32 uz2[32], ur2[32], uh2c[32];
        #pragma unroll
        for (int p = 0; p < 32; ++p) {
            uz2[p]  = packf16(U[(size_t)(2 * p) * G3 + lane],
                              U[(size_t)(2 * p + 1) * G3 + lane]);
            ur2[p]  = packf16(U[(size_t)(2 * p) * G3 + 64 + lane],
                              U[(size_t)(2 * p + 1) * G3 + 64 + lane]);
            uh2c[p] = packf16(U[(size_t)(2 * p) * G3 + 128 + lane],
                              U[(size_t)(2 * p + 1) * G3 + 128 + lane]);
        }
        const float brz = bias[G3 + lane];
        const float brr = bias[G3 + 64 + lane];
        const float brh = bias[G3 + 128 + lane];
        float h = 0.f;

        __syncthreads();

        for (int c = 0; c < NCHUNK; ++c) {
            const int buf = c & 1;

            // ---- chunk preload: all 48 gate values into registers ----
            float xzv[CHUNK], xrv[CHUNK], xhv[CHUNK];
            #pragma unroll
            for (int s = 0; s < CHUNK; ++s) {
                xzv[s] = Xb[buf][wv][s][lane];
                xrv[s] = Xb[buf][wv][s][64 + lane];
                xhv[s] = Xb[buf][wv][s][128 + lane];
            }

            // ---- 16 register-only steps ----
            #pragma unroll
            for (int s = 0; s < CHUNK; ++s) {
                const float nbh = __int_as_float(
                    __builtin_amdgcn_mov_dpp(__float_as_int(h), 0xB1, 0xF, 0xF, true));
                const u32 pk = pkrtz(h, nbh);

                u32 hs[32];
                #pragma unroll
                for (int p = 0; p < 16; ++p) {
                    hs[p]      = (u32)__builtin_amdgcn_readlane((int)pk, 2 * p);
                    hs[p + 16] = (u32)__builtin_amdgcn_readlane((int)pk, 2 * p + 32);
                }

                // ---- z chains FIRST (packed f16 fma), sigmoid overlaps rest ----
                h2v az0 = {0, 0}, az1 = {0, 0}, az2 = {0, 0}, az3 = {0, 0};
                #pragma unroll
                for (int p = 0; p < 8; ++p) {
                    az0 = pkfma(hs[p],      uz2[p],      az0);
                    az1 = pkfma(hs[p + 8],  uz2[p + 8],  az1);
                    az2 = pkfma(hs[p + 16], uz2[p + 16], az2);
                    az3 = pkfma(hs[p + 24], uz2[p + 24], az3);
                }
                az0 += az1; az2 += az3; az0 += az2;          // 3x v_pk_add_f16
                const float zpre = brz + xzv[s] + (float)az0[0] + (float)az0[1];
                const float z    = sigmoid_fast(zpre);

                // ---- r chains (packed f16 fma) + candidate (f32 dot2) ----
                h2v br0 = {0, 0}, br1 = {0, 0}, br2 = {0, 0}, br3 = {0, 0};
                float ac0 = brh, ac1 = 0.f, ac2 = 0.f, ac3 = 0.f;
                #pragma unroll
                for (int p = 0; p < 8; ++p) {
                    br0 = pkfma(hs[p],      ur2[p],      br0);
                    br1 = pkfma(hs[p + 8],  ur2[p + 8],  br1);
                    br2 = pkfma(hs[p + 16], ur2[p + 16], br2);
                    br3 = pkfma(hs[p + 24], ur2[p + 24], br3);
                    ac0 = dot2acc(hs[p],      uh2c[p],      ac0);
                    ac1 = dot2acc(hs[p + 8],  uh2c[p + 8],  ac1);
                    ac2 = dot2acc(hs[p + 16], uh2c[p + 16], ac2);
                    ac3 = dot2acc(hs[p + 24], uh2c[p + 24], ac3);
                }
                br0 += br1; br2 += br3; br0 += br2;
                const float rpre = brr + xrv[s] + (float)br0[0] + (float)br0[1];
                const float rh   = (ac0 + ac1) + (ac2 + ac3);
                const float rg   = sigmoid_fast(rpre);
                const float hh   = fmaxf(fmaf(rg, rh, xhv[s]), 0.f);
                h = fmaf(z, h - hh, hh);
            }
            __syncthreads();
        }

        // ---------------- epilogue: head + softmax (own row) ----------------
        hb[wv][lane] = h;
        WAVE_SYNC();

        float a = b1[lane];
        #pragma unroll 8
        for (int k = 0; k < UN; ++k)
            a = fmaf(hb[wv][k], W1[k * UN + lane], a);
        sc[wv][lane] = fmaxf(a, 0.f);
        WAVE_SYNC();

        if (lane < NCLS) {
            float acc = b2[lane];
            #pragma unroll 8
            for (int k = 0; k < UN; ++k)
                acc = fmaf(sc[wv][k], W2[k * NCLS + lane], acc);
            lg[wv][lane] = acc;
        }
        WAVE_SYNC();
        if (lane < NCLS) {
            float m = lg[wv][0];
            #pragma unroll
            for (int k = 1; k < NCLS; ++k) m = fmaxf(m, lg[wv][k]);
            float ss = 0.f;
            #pragma unroll
            for (int k = 0; k < NCLS; ++k) ss += __expf(lg[wv][k] - m);
            out[(r0 + wv) * NCLS + lane] = __expf(lg[wv][lane] - m) / ss;
        }
    }
}

extern "C" void kernel_launch(void* const* d_in, const int* in_sizes, int n_in,
                              void* d_out, int out_size, void* d_ws, size_t ws_size,
                              hipStream_t stream) {
    const float* inp  = (const float*)d_in[0];
    const float* W    = (const float*)d_in[1];
    const float* U    = (const float*)d_in[2];
    const float* bias = (const float*)d_in[3];
    const float* W1   = (const float*)d_in[4];
    const float* b1   = (const float*)d_in[5];
    const float* W2   = (const float*)d_in[6];
    const float* b2   = (const float*)d_in[7];
    float* out = (float*)d_out;

    gru_fused17<<<B_SZ / 2, 256, 0, stream>>>(inp, W, U, bias, W1, b1, W2, b2, out);
}

// Round 18
// 170.316 us; speedup vs baseline: 1.0869x; 1.0869x over previous
//
#include <hip/hip_runtime.h>

// Fused GRU (Keras reset_after=True, relu) for MI355X — round 18 = r16 revert.
// Best validated kernel (170.6 µs). r17's pk_fma_f16 experiment regressed
// (all f16 MAC encodings are half-rate on wave64) — restored verbatim.
//  - Wave 0/1: recurrence rows 0/1. Register-only step: X chunk-preloaded,
//    U f16-packed resident, h broadcast via dpp+cvt_pkrtz -> 32 readlane
//    -> SGPRs, 12 dot2 chains of 8, fast sigmoid (v_exp/v_rcp), z-chains
//    first so sigmoid(z) overlaps the r/candidate dots.
//  - Wave 2/3: x-proj producers (bf16x3 MFMA, W frags register-resident,
//    double-buffered Xb, one __syncthreads per 16-step chunk).
// Block = 256 thr (4 waves) = 2 batch rows. Grid = 256 = 1 block/CU, 1 pass.

#define B_SZ   512
#define T_SZ   512
#define F_SZ   128
#define UN     64
#define G3     192
#define CHUNK  16
#define NCHUNK (T_SZ / CHUNK)
#define NCLS   10
#define GP     196

using short8 = __attribute__((ext_vector_type(8))) short;
using f32x4  = __attribute__((ext_vector_type(4))) float;
using h2     = __attribute__((ext_vector_type(2))) __fp16;
typedef unsigned int u32;

union S8 { short8 s; u32 u[4]; };
union HU { h2 h; u32 u; };

__device__ __forceinline__ u32 permb(u32 a, u32 b, u32 sel) {
    return __builtin_amdgcn_perm(a, b, sel);
}
__device__ __forceinline__ unsigned short f2bf_rn(float f) {
    u32 u = __float_as_uint(f);
    u32 r = u + 0x7FFFu + ((u >> 16) & 1u);
    return (unsigned short)(r >> 16);
}
__device__ __forceinline__ float bf2f(unsigned short s) {
    return __uint_as_float(((u32)s) << 16);
}
__device__ __forceinline__ float sigmoid_fast(float x) {
    float t = -1.44269504f * x;
    float e; asm("v_exp_f32 %0, %1" : "=v"(e) : "v"(t));
    float d = 1.0f + e;
    float r; asm("v_rcp_f32 %0, %1" : "=v"(r) : "v"(d));
    return r;
}
__device__ __forceinline__ void split_pair(float f0, float f1, u32 &hi, u32 &lo) {
    u32 u0 = __float_as_uint(f0) & 0xffff0000u;
    u32 u1 = __float_as_uint(f1) & 0xffff0000u;
    float l0 = f0 - __uint_as_float(u0);
    float l1 = f1 - __uint_as_float(u1);
    hi = permb(u1, u0, 0x07060302u);
    lo = permb(__float_as_uint(l1), __float_as_uint(l0), 0x07060302u);
}
__device__ __forceinline__ u32 packf16(float f0, float f1) {
    __fp16 a = (__fp16)f0, b = (__fp16)f1;
    return (u32)__builtin_bit_cast(unsigned short, a)
         | ((u32)__builtin_bit_cast(unsigned short, b) << 16);
}
__device__ __forceinline__ float dot2acc(u32 hp, u32 up, float acc) {
#if __has_builtin(__builtin_amdgcn_fdot2)
    HU a, b; a.u = hp; b.u = up;
    return __builtin_amdgcn_fdot2(a.h, b.h, acc, false);
#else
    HU a, b; a.u = hp; b.u = up;
    acc = fmaf((float)a.h[0], (float)b.h[0], acc);
    return fmaf((float)a.h[1], (float)b.h[1], acc);
#endif
}
// pack (f0 -> lo16, f1 -> hi16) as f16 with RTZ, single instruction
__device__ __forceinline__ u32 pkrtz(float f0, float f1) {
#if __has_builtin(__builtin_amdgcn_cvt_pkrtz)
    h2 v = __builtin_amdgcn_cvt_pkrtz(f0, f1);
    return __builtin_bit_cast(u32, v);
#else
    return packf16(f0, f1);
#endif
}
#define WAVE_SYNC() asm volatile("s_waitcnt lgkmcnt(0)" ::: "memory")
#define MFMA16(A, B, C) __builtin_amdgcn_mfma_f32_16x16x32_bf16((A), (B), (C), 0, 0, 0)

__global__ __launch_bounds__(256, 1)
void gru_fused18(const float* __restrict__ inp,   // [512,512,128]
                 const float* __restrict__ W,     // [128,192]
                 const float* __restrict__ U,     // [64,192]
                 const float* __restrict__ bias,  // [2,192]
                 const float* __restrict__ W1,    // [64,64]
                 const float* __restrict__ b1,    // [64]
                 const float* __restrict__ W2,    // [64,10]
                 const float* __restrict__ b2,    // [10]
                 float* __restrict__ out)         // [512,10]
{
    const int tid  = threadIdx.x;
    const int wv   = tid >> 6;
    const int lane = tid & 63;
    const int l15  = lane & 15;
    const int l4   = lane >> 4;
    const int r0   = blockIdx.x * 2;

    __shared__ __align__(16) float Xb[2][2][CHUNK][GP];
    __shared__ float hb[2][UN];
    __shared__ float sc[2][UN];
    __shared__ float lg[2][NCLS];

    if (wv >= 2) {
        // ======================= producers =======================
        const int tb = 6 * (wv - 2);
        short8 Wh[6][4], Wl[6][4];
        float  b0c[6];
        #pragma unroll
        for (int nt = 0; nt < 6; ++nt) {
            const int col = 16 * (tb + nt) + l15;
            b0c[nt] = bias[col];
            #pragma unroll
            for (int kt = 0; kt < 4; ++kt) {
                #pragma unroll
                for (int e = 0; e < 8; ++e) {
                    float w = W[(size_t)(32 * kt + 8 * l4 + e) * G3 + col];
                    unsigned short hi = f2bf_rn(w);
                    Wh[nt][kt][e] = (short)hi;
                    Wl[nt][kt][e] = (short)f2bf_rn(w - bf2f(hi));
                }
            }
        }

        auto produce = [&](int cn) {
            const int bn = cn & 1;
            #pragma unroll
            for (int r = 0; r < 2; ++r) {
                const float* ap = inp + (size_t)(r0 + r) * T_SZ * F_SZ
                                + (size_t)(cn * CHUNK + l15) * F_SZ + 8 * l4;
                f32x4 acc[6];
                #pragma unroll
                for (int nt = 0; nt < 6; ++nt) acc[nt] = (f32x4){0.f, 0.f, 0.f, 0.f};
                #pragma unroll
                for (int kt = 0; kt < 4; ++kt) {
                    f32x4 v0 = *(const f32x4*)(ap + 32 * kt);
                    f32x4 v1 = *(const f32x4*)(ap + 32 * kt + 4);
                    S8 Ah, Al;
                    split_pair(v0[0], v0[1], Ah.u[0], Al.u[0]);
                    split_pair(v0[2], v0[3], Ah.u[1], Al.u[1]);
                    split_pair(v1[0], v1[1], Ah.u[2], Al.u[2]);
                    split_pair(v1[2], v1[3], Ah.u[3], Al.u[3]);
                    #pragma unroll
                    for (int nt = 0; nt < 6; ++nt) {
                        acc[nt] = MFMA16(Ah.s, Wh[nt][kt], acc[nt]);
                        acc[nt] = MFMA16(Al.s, Wh[nt][kt], acc[nt]);
                        acc[nt] = MFMA16(Ah.s, Wl[nt][kt], acc[nt]);
                    }
                }
                #pragma unroll
                for (int nt = 0; nt < 6; ++nt) {
                    const int col = 16 * (tb + nt) + l15;
                    #pragma unroll
                    for (int q = 0; q < 4; ++q)
                        Xb[bn][r][4 * l4 + q][col] = acc[nt][q] + b0c[nt];
                }
            }
        };

        produce(0);
        __syncthreads();
        for (int c = 0; c < NCHUNK; ++c) {
            if (c + 1 < NCHUNK) produce(c + 1);
            __syncthreads();
        }
    } else {
        // ======================= recurrence (row = wv) =======================
        u32 uz2[32], ur2[32], uh2c[32];
        #pragma unroll
        for (int p = 0; p < 32; ++p) {
            uz2[p]  = packf16(U[(size_t)(2 * p) * G3 + lane],
                              U[(size_t)(2 * p + 1) * G3 + lane]);
            ur2[p]  = packf16(U[(size_t)(2 * p) * G3 + 64 + lane],
                              U[(size_t)(2 * p + 1) * G3 + 64 + lane]);
            uh2c[p] = packf16(U[(size_t)(2 * p) * G3 + 128 + lane],
                              U[(size_t)(2 * p + 1) * G3 + 128 + lane]);
        }
        const float brz = bias[G3 + lane];
        const float brr = bias[G3 + 64 + lane];
        const float brh = bias[G3 + 128 + lane];
        float h = 0.f;

        __syncthreads();

        for (int c = 0; c < NCHUNK; ++c) {
            const int buf = c & 1;

            // ---- chunk preload: all 48 gate values into registers ----
            float xzv[CHUNK], xrv[CHUNK], xhv[CHUNK];
            #pragma unroll
            for (int s = 0; s < CHUNK; ++s) {
                xzv[s] = Xb[buf][wv][s][lane];
                xrv[s] = Xb[buf][wv][s][64 + lane];
                xhv[s] = Xb[buf][wv][s][128 + lane];
            }

            // ---- 16 register-only steps ----
            #pragma unroll
            for (int s = 0; s < CHUNK; ++s) {
                // pack h pair: 2 ops. readlane reads EVEN lanes only, where
                // (own, neighbor) = (h[2k], h[2k+1]) -> lo16=own, hi16=nb.
                const float nbh = __int_as_float(
                    __builtin_amdgcn_mov_dpp(__float_as_int(h), 0xB1, 0xF, 0xF, true));
                const u32 pk = pkrtz(h, nbh);

                u32 hs[32];
                #pragma unroll
                for (int p = 0; p < 16; ++p) {
                    hs[p]      = (u32)__builtin_amdgcn_readlane((int)pk, 2 * p);
                    hs[p + 16] = (u32)__builtin_amdgcn_readlane((int)pk, 2 * p + 32);
                }

                // ---- z chains FIRST: sigmoid(z) overlaps the ar/ac dots ----
                float az0 = brz + xzv[s], az1 = 0.f, az2 = 0.f, az3 = 0.f;
                #pragma unroll
                for (int p = 0; p < 8; ++p) {
                    az0 = dot2acc(hs[p],      uz2[p],      az0);
                    az1 = dot2acc(hs[p + 8],  uz2[p + 8],  az1);
                    az2 = dot2acc(hs[p + 16], uz2[p + 16], az2);
                    az3 = dot2acc(hs[p + 24], uz2[p + 24], az3);
                }
                const float zpre = (az0 + az1) + (az2 + az3);
                const float z    = sigmoid_fast(zpre);

                float ar0 = brr + xrv[s], ar1 = 0.f, ar2 = 0.f, ar3 = 0.f;
                float ac0 = brh,          ac1 = 0.f, ac2 = 0.f, ac3 = 0.f;
                #pragma unroll
                for (int p = 0; p < 8; ++p) {
                    ar0 = dot2acc(hs[p],      ur2[p],       ar0);
                    ar1 = dot2acc(hs[p + 8],  ur2[p + 8],   ar1);
                    ar2 = dot2acc(hs[p + 16], ur2[p + 16],  ar2);
                    ar3 = dot2acc(hs[p + 24], ur2[p + 24],  ar3);
                    ac0 = dot2acc(hs[p],      uh2c[p],      ac0);
                    ac1 = dot2acc(hs[p + 8],  uh2c[p + 8],  ac1);
                    ac2 = dot2acc(hs[p + 16], uh2c[p + 16], ac2);
                    ac3 = dot2acc(hs[p + 24], uh2c[p + 24], ac3);
                }
                const float rpre = (ar0 + ar1) + (ar2 + ar3);
                const float rh   = (ac0 + ac1) + (ac2 + ac3);
                const float rg   = sigmoid_fast(rpre);
                const float hh   = fmaxf(fmaf(rg, rh, xhv[s]), 0.f);
                h = fmaf(z, h - hh, hh);
            }
            __syncthreads();
        }

        // ---------------- epilogue: head + softmax (own row) ----------------
        hb[wv][lane] = h;
        WAVE_SYNC();

        float a = b1[lane];
        #pragma unroll 8
        for (int k = 0; k < UN; ++k)
            a = fmaf(hb[wv][k], W1[k * UN + lane], a);
        sc[wv][lane] = fmaxf(a, 0.f);
        WAVE_SYNC();

        if (lane < NCLS) {
            float acc = b2[lane];
            #pragma unroll 8
            for (int k = 0; k < UN; ++k)
                acc = fmaf(sc[wv][k], W2[k * NCLS + lane], acc);
            lg[wv][lane] = acc;
        }
        WAVE_SYNC();
        if (lane < NCLS) {
            float m = lg[wv][0];
            #pragma unroll
            for (int k = 1; k < NCLS; ++k) m = fmaxf(m, lg[wv][k]);
            float ss = 0.f;
            #pragma unroll
            for (int k = 0; k < NCLS; ++k) ss += __expf(lg[wv][k] - m);
            out[(r0 + wv) * NCLS + lane] = __expf(lg[wv][lane] - m) / ss;
        }
    }
}

extern "C" void kernel_launch(void* const* d_in, const int* in_sizes, int n_in,
                              void* d_out, int out_size, void* d_ws, size_t ws_size,
                              hipStream_t stream) {
    const float* inp  = (const float*)d_in[0];
    const float* W    = (const float*)d_in[1];
    const float* U    = (const float*)d_in[2];
    const float* bias = (const float*)d_in[3];
    const float* W1   = (const float*)d_in[4];
    const float* b1   = (const float*)d_in[5];
    const float* W2   = (const float*)d_in[6];
    const float* b2   = (const float*)d_in[7];
    float* out = (float*)d_out;

    gru_fused18<<<B_SZ / 2, 256, 0, stream>>>(inp, W, U, bias, W1, b1, W2, b2, out);
}